// Round 1
// baseline (652.831 us; speedup 1.0000x reference)
//
#include <hip/hip_runtime.h>

// GCN: 4 layers, N=50000 nodes, E=640000 edges, d=128 (last 128->40).
// h_{l+1} = relu( Dh^-1/2 A Dh^-1/2 h_l W_l )
// Strategy: build CSR (by dst) once, reuse for 4 aggregations. No float atomics.
// norm[src] pre-scale folded into previous GEMM epilogue. Last layer: GEMM
// first (128->40), then aggregate 40-dim (W commutes with node-side ops).

#define DIM 128

__global__ void deg_kernel(const int* __restrict__ dst, int* __restrict__ deg, int E) {
    int i = blockIdx.x * blockDim.x + threadIdx.x;
    if (i < E) atomicAdd(&deg[dst[i]], 1);
}

__global__ void norm_kernel(const int* __restrict__ deg, float* __restrict__ nrm, int n) {
    int i = blockIdx.x * blockDim.x + threadIdx.x;
    if (i < n) nrm[i] = rsqrtf(fmaxf((float)deg[i], 1.0f));
}

// Single-block exclusive scan: each thread owns a contiguous strip.
__global__ void scan_kernel(const int* __restrict__ deg, int* __restrict__ off, int n) {
    __shared__ int sd[1024];
    int t = threadIdx.x;
    int strip = (n + 1023) / 1024;
    int s0 = t * strip, s1 = min(s0 + strip, n);
    int sum = 0;
    for (int i = s0; i < s1; ++i) sum += deg[i];
    sd[t] = sum;
    __syncthreads();
    for (int o = 1; o < 1024; o <<= 1) {
        int x = (t >= o) ? sd[t - o] : 0;
        __syncthreads();
        sd[t] += x;
        __syncthreads();
    }
    int incl = sd[t];
    int run = incl - sum;      // exclusive prefix for this strip
    for (int i = s0; i < s1; ++i) { off[i] = run; run += deg[i]; }
    if (t == 1023) off[n] = incl;
}

__global__ void fill_kernel(const int* __restrict__ src, const int* __restrict__ dst,
                            const int* __restrict__ off, int* __restrict__ cur,
                            int* __restrict__ csr, int E) {
    int i = blockIdx.x * blockDim.x + threadIdx.x;
    if (i < E) {
        int d = dst[i];
        int p = atomicAdd(&cur[d], 1);
        csr[off[d] + p] = src[i];
    }
}

// bufA = features * norm[row]  (vectorized float4; n4 = N*32)
__global__ void scale_kernel(const float* __restrict__ f, const float* __restrict__ nrm,
                             float* __restrict__ out, int n4) {
    int i = blockIdx.x * blockDim.x + threadIdx.x;
    if (i < n4) {
        int r = i >> 5;
        float s = nrm[r];
        float4 v = ((const float4*)f)[i];
        v.x *= s; v.y *= s; v.z *= s; v.w *= s;
        ((float4*)out)[i] = v;
    }
}

// out[node] = norm[node] * sum_{s in in(node)} hin[s]   (hin already src-scaled)
template<int D>
__global__ void agg_kernel(const float* __restrict__ hin, const float* __restrict__ nrm,
                           const int* __restrict__ off, const int* __restrict__ csr,
                           float* __restrict__ out) {
    int node = blockIdx.x;
    int t = threadIdx.x;
    if (t >= D) return;
    int b = off[node], e = off[node + 1];
    float a0 = 0.f, a1 = 0.f, a2 = 0.f, a3 = 0.f;
    int i = b;
    for (; i + 4 <= e; i += 4) {
        int s0 = csr[i], s1 = csr[i + 1], s2 = csr[i + 2], s3 = csr[i + 3];
        a0 += hin[s0 * D + t];
        a1 += hin[s1 * D + t];
        a2 += hin[s2 * D + t];
        a3 += hin[s3 * D + t];
    }
    for (; i < e; ++i) a0 += hin[csr[i] * D + t];
    out[node * D + t] = (a0 + a1 + a2 + a3) * nrm[node];
}

// C[64 x OUTP] = A[64 x 128] @ W[128 x outActual] (OUTP >= outActual, zero-padded).
// Epilogue: optional relu, optional *norm[row] (pre-scale for next aggregation).
template<int OUTP, bool RELU, bool SCALE>
__global__ __launch_bounds__(256) void gemm_kernel(
        const float* __restrict__ A, const float* __restrict__ W,
        const float* __restrict__ nrm, float* __restrict__ out,
        int n, int outActual) {
    constexpr int TC  = OUTP / 8;    // threads across columns
    constexpr int TR  = 256 / TC;    // threads across rows
    constexpr int RPT = 64 / TR;     // rows per thread
    constexpr int WS  = OUTP + 4;    // padded LDS strides (bank-conflict relief)
    constexpr int AS  = DIM + 4;
    __shared__ float Ws[128 * WS];
    __shared__ float As[64 * AS];
    int t = threadIdx.x;
    int row0 = blockIdx.x * 64;

    for (int idx = t; idx < 128 * OUTP; idx += 256) {
        int k = idx / OUTP, c = idx % OUTP;
        Ws[k * WS + c] = (c < outActual) ? W[k * outActual + c] : 0.f;
    }
    for (int q = t; q < 64 * 32; q += 256) {          // float4 granularity
        int r = q >> 5, c4 = q & 31;
        int row = row0 + r;
        float4 v = (row < n) ? *(const float4*)&A[row * DIM + c4 * 4]
                             : make_float4(0.f, 0.f, 0.f, 0.f);
        *(float4*)&As[r * AS + c4 * 4] = v;
    }
    __syncthreads();

    int tr = t / TC, tc = t % TC;
    float acc[RPT][8];
#pragma unroll
    for (int i = 0; i < RPT; ++i)
#pragma unroll
        for (int j = 0; j < 8; ++j) acc[i][j] = 0.f;

#pragma unroll 4
    for (int k = 0; k < 128; ++k) {
        float4 w0 = *(const float4*)&Ws[k * WS + tc * 8];
        float4 w1 = *(const float4*)&Ws[k * WS + tc * 8 + 4];
#pragma unroll
        for (int i = 0; i < RPT; ++i) {
            float a = As[(tr * RPT + i) * AS + k];
            acc[i][0] += a * w0.x; acc[i][1] += a * w0.y;
            acc[i][2] += a * w0.z; acc[i][3] += a * w0.w;
            acc[i][4] += a * w1.x; acc[i][5] += a * w1.y;
            acc[i][6] += a * w1.z; acc[i][7] += a * w1.w;
        }
    }

#pragma unroll
    for (int i = 0; i < RPT; ++i) {
        int row = row0 + tr * RPT + i;
        if (row >= n) continue;
        float s = SCALE ? nrm[row] : 1.f;
#pragma unroll
        for (int j = 0; j < 8; ++j) {
            int c = tc * 8 + j;
            if (c < outActual) {
                float v = acc[i][j];
                if (RELU) v = fmaxf(v, 0.f);
                out[row * outActual + c] = v * s;
            }
        }
    }
}

extern "C" void kernel_launch(void* const* d_in, const int* in_sizes, int n_in,
                              void* d_out, int out_size, void* d_ws, size_t ws_size,
                              hipStream_t stream) {
    const float* features = (const float*)d_in[0];
    const int*   edges    = (const int*)d_in[1];
    const float* W0       = (const float*)d_in[2];
    const float* W1       = (const float*)d_in[3];
    const float* W2       = (const float*)d_in[4];
    const float* W3       = (const float*)d_in[5];

    const int N = in_sizes[0] / DIM;       // 50000
    const int E = in_sizes[1] / 2;         // 640000
    const int DOUT = out_size / N;         // 40
    const int* src = edges;
    const int* dst = edges + E;

    char* p = (char*)d_ws;
    float* bufA = (float*)p;  p += (size_t)N * DIM * 4;
    float* bufB = (float*)p;  p += (size_t)N * DIM * 4;
    float* nrm  = (float*)p;  p += (size_t)N * 4;
    int*   deg  = (int*)p;    p += (size_t)N * 4;
    int*   cur  = (int*)p;    p += (size_t)N * 4;   // adjacent to deg -> one memset
    int*   off  = (int*)p;    p += (size_t)(N + 1) * 4;
    int*   csr  = (int*)p;    p += (size_t)E * 4;
    (void)ws_size; (void)n_in;

    hipMemsetAsync(deg, 0, (size_t)N * 2 * sizeof(int), stream);  // deg + cur

    int eb = (E + 255) / 256;
    int nb = (N + 255) / 256;
    deg_kernel <<<eb, 256, 0, stream>>>(dst, deg, E);
    norm_kernel<<<nb, 256, 0, stream>>>(deg, nrm, N);
    scan_kernel<<<1, 1024, 0, stream>>>(deg, off, N);
    fill_kernel<<<eb, 256, 0, stream>>>(src, dst, off, cur, csr, E);

    int n4 = N * (DIM / 4);
    scale_kernel<<<(n4 + 255) / 256, 256, 0, stream>>>(features, nrm, bufA, n4);

    int gb = (N + 63) / 64;
    // layer 0..2: agg(128) then GEMM 128x128 with relu + norm pre-scale
    agg_kernel<DIM><<<N, DIM, 0, stream>>>(bufA, nrm, off, csr, bufB);
    gemm_kernel<128, true, true><<<gb, 256, 0, stream>>>(bufB, W0, nrm, bufA, N, 128);

    agg_kernel<DIM><<<N, DIM, 0, stream>>>(bufA, nrm, off, csr, bufB);
    gemm_kernel<128, true, true><<<gb, 256, 0, stream>>>(bufB, W1, nrm, bufA, N, 128);

    agg_kernel<DIM><<<N, DIM, 0, stream>>>(bufA, nrm, off, csr, bufB);
    gemm_kernel<128, true, true><<<gb, 256, 0, stream>>>(bufB, W2, nrm, bufA, N, 128);

    // layer 3: GEMM first (128->40, no relu, no scale), then aggregate 40-dim
    gemm_kernel<64, false, false><<<gb, 256, 0, stream>>>(bufA, W3, nrm, bufB, N, DOUT);
    agg_kernel<40><<<N, 64, 0, stream>>>(bufB, nrm, off, csr, (float*)d_out);
}

// Round 2
// 451.177 us; speedup vs baseline: 1.4470x; 1.4470x over previous
//
#include <hip/hip_runtime.h>

// GCN: 4 layers, N=50000, E=640000, d=128 (last 128->40).
// CSR built once (int atomics only), reused 4x. norm[src] pre-scale folded
// into previous GEMM epilogue. Last layer: GEMM first (128->40), then agg.
// R2: GEMM rewritten for occupancy — only A-tile in LDS (32 KB, unpadded,
// broadcast reads), W streamed from L2. Agg: one wave per node.

#define DIM 128

__global__ void deg_kernel(const int* __restrict__ dst, int* __restrict__ deg, int E) {
    int i = blockIdx.x * blockDim.x + threadIdx.x;
    if (i < E) atomicAdd(&deg[dst[i]], 1);
}

__global__ void norm_kernel(const int* __restrict__ deg, float* __restrict__ nrm, int n) {
    int i = blockIdx.x * blockDim.x + threadIdx.x;
    if (i < n) nrm[i] = rsqrtf(fmaxf((float)deg[i], 1.0f));
}

// Single-block exclusive scan: each thread owns a contiguous strip.
__global__ void scan_kernel(const int* __restrict__ deg, int* __restrict__ off, int n) {
    __shared__ int sd[1024];
    int t = threadIdx.x;
    int strip = (n + 1023) / 1024;
    int s0 = t * strip, s1 = min(s0 + strip, n);
    int sum = 0;
    for (int i = s0; i < s1; ++i) sum += deg[i];
    sd[t] = sum;
    __syncthreads();
    for (int o = 1; o < 1024; o <<= 1) {
        int x = (t >= o) ? sd[t - o] : 0;
        __syncthreads();
        sd[t] += x;
        __syncthreads();
    }
    int incl = sd[t];
    int run = incl - sum;
    for (int i = s0; i < s1; ++i) { off[i] = run; run += deg[i]; }
    if (t == 1023) off[n] = incl;
}

__global__ void fill_kernel(const int* __restrict__ src, const int* __restrict__ dst,
                            const int* __restrict__ off, int* __restrict__ cur,
                            int* __restrict__ csr, int E) {
    int i = blockIdx.x * blockDim.x + threadIdx.x;
    if (i < E) {
        int d = dst[i];
        int p = atomicAdd(&cur[d], 1);
        csr[off[d] + p] = src[i];
    }
}

// bufA = features * norm[row]
__global__ void scale_kernel(const float* __restrict__ f, const float* __restrict__ nrm,
                             float* __restrict__ out, int n4) {
    int i = blockIdx.x * blockDim.x + threadIdx.x;
    if (i < n4) {
        int r = i >> 5;
        float s = nrm[r];
        float4 v = ((const float4*)f)[i];
        v.x *= s; v.y *= s; v.z *= s; v.w *= s;
        ((float4*)out)[i] = v;
    }
}

// One 64-lane wave per node. out[node] = nrm[node] * sum_{s in in(node)} hin[s].
template<int D>
__global__ __launch_bounds__(256) void agg_kernel(
        const float* __restrict__ hin, const float* __restrict__ nrm,
        const int* __restrict__ off, const int* __restrict__ csr,
        float* __restrict__ out, int N) {
    int lane = threadIdx.x & 63;
    int node = blockIdx.x * 4 + (threadIdx.x >> 6);
    if (node >= N) return;
    int b = off[node], e = off[node + 1];
    float s = nrm[node];
    if (D == 128) {
        int c = lane << 1;                 // float2 per lane, 512B per edge row
        float a0x = 0, a0y = 0, a1x = 0, a1y = 0;
        float a2x = 0, a2y = 0, a3x = 0, a3y = 0;
        int i = b;
        for (; i + 4 <= e; i += 4) {
            int s0 = csr[i], s1 = csr[i + 1], s2 = csr[i + 2], s3 = csr[i + 3];
            float2 v0 = *(const float2*)&hin[(size_t)s0 * 128 + c];
            float2 v1 = *(const float2*)&hin[(size_t)s1 * 128 + c];
            float2 v2 = *(const float2*)&hin[(size_t)s2 * 128 + c];
            float2 v3 = *(const float2*)&hin[(size_t)s3 * 128 + c];
            a0x += v0.x; a0y += v0.y; a1x += v1.x; a1y += v1.y;
            a2x += v2.x; a2y += v2.y; a3x += v3.x; a3y += v3.y;
        }
        for (; i < e; ++i) {
            float2 v = *(const float2*)&hin[(size_t)csr[i] * 128 + c];
            a0x += v.x; a0y += v.y;
        }
        float2 r;
        r.x = (a0x + a1x + a2x + a3x) * s;
        r.y = (a0y + a1y + a2y + a3y) * s;
        *(float2*)&out[(size_t)node * 128 + c] = r;
    } else {
        if (lane >= D) return;
        float a0 = 0, a1 = 0, a2 = 0, a3 = 0;
        int i = b;
        for (; i + 4 <= e; i += 4) {
            a0 += hin[(size_t)csr[i]     * D + lane];
            a1 += hin[(size_t)csr[i + 1] * D + lane];
            a2 += hin[(size_t)csr[i + 2] * D + lane];
            a3 += hin[(size_t)csr[i + 3] * D + lane];
        }
        for (; i < e; ++i) a0 += hin[(size_t)csr[i] * D + lane];
        out[(size_t)node * D + lane] = (a0 + a1 + a2 + a3) * s;
    }
}

// C[64 x 32*CW] = A[64 x 128] @ W[128 x outw]. A-tile in LDS (32 KB, unpadded);
// W streamed from global (L2-resident, shared by all blocks).
// CW=4: outw==128, float4 W loads. CW=2: outw<=64, guarded scalar W loads.
// Thread: tr = t/32 owns rows tr*8..tr*8+7; tc = t%32 owns CW cols.
template<int CW, bool RELU, bool SCALE>
__global__ __launch_bounds__(256) void gemm_kernel(
        const float* __restrict__ A, const float* __restrict__ W,
        const float* __restrict__ nrm, float* __restrict__ out,
        int n, int outw) {
    __shared__ float As[64 * DIM];
    int t = threadIdx.x;
    int row0 = blockIdx.x * 64;

    for (int q = t; q < 64 * 32; q += 256) {
        int r = q >> 5, c4 = q & 31;
        int row = row0 + r;
        float4 v = (row < n) ? *(const float4*)&A[(size_t)row * DIM + c4 * 4]
                             : make_float4(0.f, 0.f, 0.f, 0.f);
        *(float4*)&As[r * DIM + c4 * 4] = v;
    }
    __syncthreads();

    int tc = t & 31, tr = t >> 5;
    float acc[8][CW];
#pragma unroll
    for (int i = 0; i < 8; ++i)
#pragma unroll
        for (int j = 0; j < CW; ++j) acc[i][j] = 0.f;

    for (int k4 = 0; k4 < 32; ++k4) {
        float w[4][CW];
#pragma unroll
        for (int dk = 0; dk < 4; ++dk) {
            int k = k4 * 4 + dk;
            if (CW == 4) {
                float4 wv = *(const float4*)&W[(size_t)k * outw + tc * 4];
                w[dk][0] = wv.x; w[dk][1] = wv.y; w[dk][2] = wv.z; w[dk][3] = wv.w;
            } else {
                int c0 = tc * 2, c1 = c0 + 1;
                w[dk][0] = (c0 < outw) ? W[(size_t)k * outw + c0] : 0.f;
                w[dk][1] = (c1 < outw) ? W[(size_t)k * outw + c1] : 0.f;
            }
        }
#pragma unroll
        for (int i = 0; i < 8; ++i) {
            // 2 distinct addresses per wave -> broadcast, conflict-free
            float4 a = *(const float4*)&As[(tr * 8 + i) * DIM + k4 * 4];
            float av[4] = {a.x, a.y, a.z, a.w};
#pragma unroll
            for (int dk = 0; dk < 4; ++dk)
#pragma unroll
                for (int j = 0; j < CW; ++j)
                    acc[i][j] += av[dk] * w[dk][j];
        }
    }

#pragma unroll
    for (int i = 0; i < 8; ++i) {
        int row = row0 + tr * 8 + i;
        if (row >= n) continue;
        float s = SCALE ? nrm[row] : 1.f;
        if (CW == 4) {
            float4 v = make_float4(acc[i][0], acc[i][1], acc[i][2], acc[i][3]);
            if (RELU) {
                v.x = fmaxf(v.x, 0.f); v.y = fmaxf(v.y, 0.f);
                v.z = fmaxf(v.z, 0.f); v.w = fmaxf(v.w, 0.f);
            }
            v.x *= s; v.y *= s; v.z *= s; v.w *= s;
            *(float4*)&out[(size_t)row * outw + tc * 4] = v;
        } else {
#pragma unroll
            for (int j = 0; j < CW; ++j) {
                int c = tc * CW + j;
                if (c < outw) {
                    float v = acc[i][j];
                    if (RELU) v = fmaxf(v, 0.f);
                    out[(size_t)row * outw + c] = v * s;
                }
            }
        }
    }
}

extern "C" void kernel_launch(void* const* d_in, const int* in_sizes, int n_in,
                              void* d_out, int out_size, void* d_ws, size_t ws_size,
                              hipStream_t stream) {
    const float* features = (const float*)d_in[0];
    const int*   edges    = (const int*)d_in[1];
    const float* W0       = (const float*)d_in[2];
    const float* W1       = (const float*)d_in[3];
    const float* W2       = (const float*)d_in[4];
    const float* W3       = (const float*)d_in[5];

    const int N = in_sizes[0] / DIM;       // 50000
    const int E = in_sizes[1] / 2;         // 640000
    const int DOUT = out_size / N;         // 40
    const int* src = edges;
    const int* dst = edges + E;

    char* p = (char*)d_ws;
    float* bufA = (float*)p;  p += (size_t)N * DIM * 4;
    float* bufB = (float*)p;  p += (size_t)N * DIM * 4;
    float* nrm  = (float*)p;  p += (size_t)N * 4;
    int*   deg  = (int*)p;    p += (size_t)N * 4;
    int*   cur  = (int*)p;    p += (size_t)N * 4;   // adjacent to deg -> one memset
    int*   off  = (int*)p;    p += (size_t)(N + 1) * 4;
    int*   csr  = (int*)p;    p += (size_t)E * 4;
    (void)ws_size; (void)n_in;

    hipMemsetAsync(deg, 0, (size_t)N * 2 * sizeof(int), stream);  // deg + cur

    int eb = (E + 255) / 256;
    int nb = (N + 255) / 256;
    deg_kernel <<<eb, 256, 0, stream>>>(dst, deg, E);
    norm_kernel<<<nb, 256, 0, stream>>>(deg, nrm, N);
    scan_kernel<<<1, 1024, 0, stream>>>(deg, off, N);
    fill_kernel<<<eb, 256, 0, stream>>>(src, dst, off, cur, csr, E);

    int n4 = N * (DIM / 4);
    scale_kernel<<<(n4 + 255) / 256, 256, 0, stream>>>(features, nrm, bufA, n4);

    int gb = (N + 63) / 64;
    int ab = (N + 3) / 4;
    // layers 0..2: agg(128) then GEMM 128x128 with relu + norm pre-scale
    agg_kernel<DIM><<<ab, 256, 0, stream>>>(bufA, nrm, off, csr, bufB, N);
    gemm_kernel<4, true, true><<<gb, 256, 0, stream>>>(bufB, W0, nrm, bufA, N, 128);

    agg_kernel<DIM><<<ab, 256, 0, stream>>>(bufA, nrm, off, csr, bufB, N);
    gemm_kernel<4, true, true><<<gb, 256, 0, stream>>>(bufB, W1, nrm, bufA, N, 128);

    agg_kernel<DIM><<<ab, 256, 0, stream>>>(bufA, nrm, off, csr, bufB, N);
    gemm_kernel<4, true, true><<<gb, 256, 0, stream>>>(bufB, W2, nrm, bufA, N, 128);

    // layer 3: GEMM first (128->40, no relu, no scale), then aggregate 40-dim
    gemm_kernel<2, false, false><<<gb, 256, 0, stream>>>(bufA, W3, nrm, bufB, N, DOUT);
    agg_kernel<40><<<ab, 256, 0, stream>>>(bufB, nrm, off, csr, (float*)d_out, N);
}

// Round 3
// 381.936 us; speedup vs baseline: 1.7093x; 1.1813x over previous
//
#include <hip/hip_runtime.h>

// GCN: 4 layers, N=50000, E=640000, d=128 (last 128->40).
// CSR built once (int atomics only), reused 4x. norm[src] pre-scale folded
// into previous GEMM epilogue. Last layer: GEMM first (128->40), then agg.
// R2: GEMM = A-tile-only LDS + W streamed from L2; agg = one wave/node.
// R3: single-block scan (76us, latency-bound) -> 3-phase parallel scan
//     (chunk sums + norm fused / 1-wave scan of 49 sums / coalesced int4
//     offset write).

#define DIM 128
#define CHUNK 1024           // elements per scan block (256 thr x int4)

__global__ void deg_kernel(const int* __restrict__ dst, int* __restrict__ deg, int E) {
    int i = blockIdx.x * blockDim.x + threadIdx.x;
    if (i < E) atomicAdd(&deg[dst[i]], 1);
}

// Phase A: per-chunk sums of deg; also computes nrm = rsqrt(max(deg,1)).
__global__ __launch_bounds__(256) void scanA_kernel(
        const int* __restrict__ deg, float* __restrict__ nrm,
        int* __restrict__ bsum, int n) {
    int b = blockIdx.x, t = threadIdx.x;
    int base = b * CHUNK + t * 4;
    int s = 0;
    if (base + 3 < n) {
        int4 d = *(const int4*)&deg[base];
        s = d.x + d.y + d.z + d.w;
        float4 r;
        r.x = rsqrtf(fmaxf((float)d.x, 1.0f));
        r.y = rsqrtf(fmaxf((float)d.y, 1.0f));
        r.z = rsqrtf(fmaxf((float)d.z, 1.0f));
        r.w = rsqrtf(fmaxf((float)d.w, 1.0f));
        *(float4*)&nrm[base] = r;
    } else {
        for (int j = 0; j < 4; ++j) {
            int idx = base + j;
            if (idx < n) {
                int d = deg[idx];
                s += d;
                nrm[idx] = rsqrtf(fmaxf((float)d, 1.0f));
            }
        }
    }
    for (int o = 32; o; o >>= 1) s += __shfl_down(s, o, 64);
    __shared__ int ws[4];
    if ((t & 63) == 0) ws[t >> 6] = s;
    __syncthreads();
    if (t == 0) bsum[b] = ws[0] + ws[1] + ws[2] + ws[3];
}

// Phase B: exclusive scan of bsum[G] in one wave (G <= 64); writes off[n]=total.
__global__ void scanB_kernel(int* __restrict__ bsum, int* __restrict__ off,
                             int G, int n) {
    int t = threadIdx.x;
    int orig = (t < G) ? bsum[t] : 0;
    int v = orig;
    for (int o = 1; o < 64; o <<= 1) {
        int u = __shfl_up(v, o, 64);
        if (t >= o) v += u;
    }
    if (t < G) bsum[t] = v - orig;          // exclusive
    if (t == G - 1) off[n] = v;             // grand total
}

// Phase C: off[i] = bsum[chunk] + prefix within chunk. int4 coalesced.
__global__ __launch_bounds__(256) void scanC_kernel(
        const int* __restrict__ deg, const int* __restrict__ bsum,
        int* __restrict__ off, int n) {
    int b = blockIdx.x, t = threadIdx.x;
    int base = b * CHUNK + t * 4;
    int d0 = 0, d1 = 0, d2 = 0, d3 = 0;
    if (base + 3 < n) {
        int4 d = *(const int4*)&deg[base];
        d0 = d.x; d1 = d.y; d2 = d.z; d3 = d.w;
    } else {
        if (base     < n) d0 = deg[base];
        if (base + 1 < n) d1 = deg[base + 1];
        if (base + 2 < n) d2 = deg[base + 2];
    }
    int tot = d0 + d1 + d2 + d3;
    int v = tot;
    for (int o = 1; o < 64; o <<= 1) {
        int u = __shfl_up(v, o, 64);
        if ((t & 63) >= o) v += u;
    }
    __shared__ int wsum[4];
    if ((t & 63) == 63) wsum[t >> 6] = v;
    __syncthreads();
    int wbase = 0;
    for (int w = 0; w < (t >> 6); ++w) wbase += wsum[w];
    int p = bsum[b] + wbase + (v - tot);    // exclusive prefix of this thread
    if (base + 3 < n) {
        int4 o4 = make_int4(p, p + d0, p + d0 + d1, p + d0 + d1 + d2);
        *(int4*)&off[base] = o4;
    } else {
        if (base     < n) off[base]     = p;
        if (base + 1 < n) off[base + 1] = p + d0;
        if (base + 2 < n) off[base + 2] = p + d0 + d1;
    }
}

__global__ void fill_kernel(const int* __restrict__ src, const int* __restrict__ dst,
                            const int* __restrict__ off, int* __restrict__ cur,
                            int* __restrict__ csr, int E) {
    int i = blockIdx.x * blockDim.x + threadIdx.x;
    if (i < E) {
        int d = dst[i];
        int p = atomicAdd(&cur[d], 1);
        csr[off[d] + p] = src[i];
    }
}

// bufA = features * norm[row]
__global__ void scale_kernel(const float* __restrict__ f, const float* __restrict__ nrm,
                             float* __restrict__ out, int n4) {
    int i = blockIdx.x * blockDim.x + threadIdx.x;
    if (i < n4) {
        int r = i >> 5;
        float s = nrm[r];
        float4 v = ((const float4*)f)[i];
        v.x *= s; v.y *= s; v.z *= s; v.w *= s;
        ((float4*)out)[i] = v;
    }
}

// One 64-lane wave per node. out[node] = nrm[node] * sum_{s in in(node)} hin[s].
template<int D>
__global__ __launch_bounds__(256) void agg_kernel(
        const float* __restrict__ hin, const float* __restrict__ nrm,
        const int* __restrict__ off, const int* __restrict__ csr,
        float* __restrict__ out, int N) {
    int lane = threadIdx.x & 63;
    int node = blockIdx.x * 4 + (threadIdx.x >> 6);
    if (node >= N) return;
    int b = off[node], e = off[node + 1];
    float s = nrm[node];
    if (D == 128) {
        int c = lane << 1;                 // float2 per lane, 512B per edge row
        float a0x = 0, a0y = 0, a1x = 0, a1y = 0;
        float a2x = 0, a2y = 0, a3x = 0, a3y = 0;
        int i = b;
        for (; i + 4 <= e; i += 4) {
            int s0 = csr[i], s1 = csr[i + 1], s2 = csr[i + 2], s3 = csr[i + 3];
            float2 v0 = *(const float2*)&hin[(size_t)s0 * 128 + c];
            float2 v1 = *(const float2*)&hin[(size_t)s1 * 128 + c];
            float2 v2 = *(const float2*)&hin[(size_t)s2 * 128 + c];
            float2 v3 = *(const float2*)&hin[(size_t)s3 * 128 + c];
            a0x += v0.x; a0y += v0.y; a1x += v1.x; a1y += v1.y;
            a2x += v2.x; a2y += v2.y; a3x += v3.x; a3y += v3.y;
        }
        for (; i < e; ++i) {
            float2 v = *(const float2*)&hin[(size_t)csr[i] * 128 + c];
            a0x += v.x; a0y += v.y;
        }
        float2 r;
        r.x = (a0x + a1x + a2x + a3x) * s;
        r.y = (a0y + a1y + a2y + a3y) * s;
        *(float2*)&out[(size_t)node * 128 + c] = r;
    } else {
        if (lane >= D) return;
        float a0 = 0, a1 = 0, a2 = 0, a3 = 0;
        int i = b;
        for (; i + 4 <= e; i += 4) {
            a0 += hin[(size_t)csr[i]     * D + lane];
            a1 += hin[(size_t)csr[i + 1] * D + lane];
            a2 += hin[(size_t)csr[i + 2] * D + lane];
            a3 += hin[(size_t)csr[i + 3] * D + lane];
        }
        for (; i < e; ++i) a0 += hin[(size_t)csr[i] * D + lane];
        out[(size_t)node * D + lane] = (a0 + a1 + a2 + a3) * s;
    }
}

// C[64 x 32*CW] = A[64 x 128] @ W[128 x outw]. A-tile in LDS (32 KB, unpadded);
// W streamed from global (L2-resident, shared by all blocks).
template<int CW, bool RELU, bool SCALE>
__global__ __launch_bounds__(256) void gemm_kernel(
        const float* __restrict__ A, const float* __restrict__ W,
        const float* __restrict__ nrm, float* __restrict__ out,
        int n, int outw) {
    __shared__ float As[64 * DIM];
    int t = threadIdx.x;
    int row0 = blockIdx.x * 64;

    for (int q = t; q < 64 * 32; q += 256) {
        int r = q >> 5, c4 = q & 31;
        int row = row0 + r;
        float4 v = (row < n) ? *(const float4*)&A[(size_t)row * DIM + c4 * 4]
                             : make_float4(0.f, 0.f, 0.f, 0.f);
        *(float4*)&As[r * DIM + c4 * 4] = v;
    }
    __syncthreads();

    int tc = t & 31, tr = t >> 5;
    float acc[8][CW];
#pragma unroll
    for (int i = 0; i < 8; ++i)
#pragma unroll
        for (int j = 0; j < CW; ++j) acc[i][j] = 0.f;

    for (int k4 = 0; k4 < 32; ++k4) {
        float w[4][CW];
#pragma unroll
        for (int dk = 0; dk < 4; ++dk) {
            int k = k4 * 4 + dk;
            if (CW == 4) {
                float4 wv = *(const float4*)&W[(size_t)k * outw + tc * 4];
                w[dk][0] = wv.x; w[dk][1] = wv.y; w[dk][2] = wv.z; w[dk][3] = wv.w;
            } else {
                int c0 = tc * 2, c1 = c0 + 1;
                w[dk][0] = (c0 < outw) ? W[(size_t)k * outw + c0] : 0.f;
                w[dk][1] = (c1 < outw) ? W[(size_t)k * outw + c1] : 0.f;
            }
        }
#pragma unroll
        for (int i = 0; i < 8; ++i) {
            float4 a = *(const float4*)&As[(tr * 8 + i) * DIM + k4 * 4];
            float av[4] = {a.x, a.y, a.z, a.w};
#pragma unroll
            for (int dk = 0; dk < 4; ++dk)
#pragma unroll
                for (int j = 0; j < CW; ++j)
                    acc[i][j] += av[dk] * w[dk][j];
        }
    }

#pragma unroll
    for (int i = 0; i < 8; ++i) {
        int row = row0 + tr * 8 + i;
        if (row >= n) continue;
        float s = SCALE ? nrm[row] : 1.f;
        if (CW == 4) {
            float4 v = make_float4(acc[i][0], acc[i][1], acc[i][2], acc[i][3]);
            if (RELU) {
                v.x = fmaxf(v.x, 0.f); v.y = fmaxf(v.y, 0.f);
                v.z = fmaxf(v.z, 0.f); v.w = fmaxf(v.w, 0.f);
            }
            v.x *= s; v.y *= s; v.z *= s; v.w *= s;
            *(float4*)&out[(size_t)row * outw + tc * 4] = v;
        } else {
#pragma unroll
            for (int j = 0; j < CW; ++j) {
                int c = tc * CW + j;
                if (c < outw) {
                    float v = acc[i][j];
                    if (RELU) v = fmaxf(v, 0.f);
                    out[(size_t)row * outw + c] = v * s;
                }
            }
        }
    }
}

extern "C" void kernel_launch(void* const* d_in, const int* in_sizes, int n_in,
                              void* d_out, int out_size, void* d_ws, size_t ws_size,
                              hipStream_t stream) {
    const float* features = (const float*)d_in[0];
    const int*   edges    = (const int*)d_in[1];
    const float* W0       = (const float*)d_in[2];
    const float* W1       = (const float*)d_in[3];
    const float* W2       = (const float*)d_in[4];
    const float* W3       = (const float*)d_in[5];

    const int N = in_sizes[0] / DIM;       // 50000
    const int E = in_sizes[1] / 2;         // 640000
    const int DOUT = out_size / N;         // 40
    const int* src = edges;
    const int* dst = edges + E;

    char* p = (char*)d_ws;
    float* bufA = (float*)p;  p += (size_t)N * DIM * 4;
    float* bufB = (float*)p;  p += (size_t)N * DIM * 4;
    float* nrm  = (float*)p;  p += (size_t)N * 4;
    int*   deg  = (int*)p;    p += (size_t)N * 4;
    int*   cur  = (int*)p;    p += (size_t)N * 4;   // adjacent to deg -> one memset
    int*   off  = (int*)p;    p += (size_t)(N + 1) * 4;
    int*   bsum = (int*)p;    p += 64 * 4;
    int*   csr  = (int*)p;    p += (size_t)E * 4;
    (void)ws_size; (void)n_in;

    hipMemsetAsync(deg, 0, (size_t)N * 2 * sizeof(int), stream);  // deg + cur

    int eb = (E + 255) / 256;
    int G  = (N + CHUNK - 1) / CHUNK;      // 49 chunks
    deg_kernel <<<eb, 256, 0, stream>>>(dst, deg, E);
    scanA_kernel<<<G, 256, 0, stream>>>(deg, nrm, bsum, N);
    scanB_kernel<<<1, 64, 0, stream>>>(bsum, off, G, N);
    scanC_kernel<<<G, 256, 0, stream>>>(deg, bsum, off, N);
    fill_kernel<<<eb, 256, 0, stream>>>(src, dst, off, cur, csr, E);

    int n4 = N * (DIM / 4);
    scale_kernel<<<(n4 + 255) / 256, 256, 0, stream>>>(features, nrm, bufA, n4);

    int gb = (N + 63) / 64;
    int ab = (N + 3) / 4;
    // layers 0..2: agg(128) then GEMM 128x128 with relu + norm pre-scale
    agg_kernel<DIM><<<ab, 256, 0, stream>>>(bufA, nrm, off, csr, bufB, N);
    gemm_kernel<4, true, true><<<gb, 256, 0, stream>>>(bufB, W0, nrm, bufA, N, 128);

    agg_kernel<DIM><<<ab, 256, 0, stream>>>(bufA, nrm, off, csr, bufB, N);
    gemm_kernel<4, true, true><<<gb, 256, 0, stream>>>(bufB, W1, nrm, bufA, N, 128);

    agg_kernel<DIM><<<ab, 256, 0, stream>>>(bufA, nrm, off, csr, bufB, N);
    gemm_kernel<4, true, true><<<gb, 256, 0, stream>>>(bufB, W2, nrm, bufA, N, 128);

    // layer 3: GEMM first (128->40, no relu, no scale), then aggregate 40-dim
    gemm_kernel<2, false, false><<<gb, 256, 0, stream>>>(bufA, W3, nrm, bufB, N, DOUT);
    agg_kernel<40><<<ab, 256, 0, stream>>>(bufB, nrm, off, csr, (float*)d_out, N);
}

// Round 4
// 371.670 us; speedup vs baseline: 1.7565x; 1.0276x over previous
//
#include <hip/hip_runtime.h>

// GCN: 4 layers, N=50000, E=640000, d=128 (last 128->40).
// CSR built once (int atomics only), reused 4x.
// R3: 3-phase parallel scan. R4: agg+GEMM fused per layer (agg -> LDS A-tile
// -> GEMM), float4 half-wave gather (8 edges in flight/wave), norm[src]
// prescale folded into layer-0 gather (scale_kernel deleted).

#define DIM 128
#define CHUNK 1024

__global__ void deg_kernel(const int* __restrict__ dst, int* __restrict__ deg, int E) {
    int i = blockIdx.x * blockDim.x + threadIdx.x;
    if (i < E) atomicAdd(&deg[dst[i]], 1);
}

// Phase A: per-chunk sums of deg; also computes nrm = rsqrt(max(deg,1)).
__global__ __launch_bounds__(256) void scanA_kernel(
        const int* __restrict__ deg, float* __restrict__ nrm,
        int* __restrict__ bsum, int n) {
    int b = blockIdx.x, t = threadIdx.x;
    int base = b * CHUNK + t * 4;
    int s = 0;
    if (base + 3 < n) {
        int4 d = *(const int4*)&deg[base];
        s = d.x + d.y + d.z + d.w;
        float4 r;
        r.x = rsqrtf(fmaxf((float)d.x, 1.0f));
        r.y = rsqrtf(fmaxf((float)d.y, 1.0f));
        r.z = rsqrtf(fmaxf((float)d.z, 1.0f));
        r.w = rsqrtf(fmaxf((float)d.w, 1.0f));
        *(float4*)&nrm[base] = r;
    } else {
        for (int j = 0; j < 4; ++j) {
            int idx = base + j;
            if (idx < n) {
                int d = deg[idx];
                s += d;
                nrm[idx] = rsqrtf(fmaxf((float)d, 1.0f));
            }
        }
    }
    for (int o = 32; o; o >>= 1) s += __shfl_down(s, o, 64);
    __shared__ int ws[4];
    if ((t & 63) == 0) ws[t >> 6] = s;
    __syncthreads();
    if (t == 0) bsum[b] = ws[0] + ws[1] + ws[2] + ws[3];
}

// Phase B: exclusive scan of bsum[G] in one wave (G <= 64); writes off[n]=total.
__global__ void scanB_kernel(int* __restrict__ bsum, int* __restrict__ off,
                             int G, int n) {
    int t = threadIdx.x;
    int orig = (t < G) ? bsum[t] : 0;
    int v = orig;
    for (int o = 1; o < 64; o <<= 1) {
        int u = __shfl_up(v, o, 64);
        if (t >= o) v += u;
    }
    if (t < G) bsum[t] = v - orig;          // exclusive
    if (t == G - 1) off[n] = v;             // grand total
}

// Phase C: off[i] = bsum[chunk] + prefix within chunk. int4 coalesced.
__global__ __launch_bounds__(256) void scanC_kernel(
        const int* __restrict__ deg, const int* __restrict__ bsum,
        int* __restrict__ off, int n) {
    int b = blockIdx.x, t = threadIdx.x;
    int base = b * CHUNK + t * 4;
    int d0 = 0, d1 = 0, d2 = 0, d3 = 0;
    if (base + 3 < n) {
        int4 d = *(const int4*)&deg[base];
        d0 = d.x; d1 = d.y; d2 = d.z; d3 = d.w;
    } else {
        if (base     < n) d0 = deg[base];
        if (base + 1 < n) d1 = deg[base + 1];
        if (base + 2 < n) d2 = deg[base + 2];
    }
    int tot = d0 + d1 + d2 + d3;
    int v = tot;
    for (int o = 1; o < 64; o <<= 1) {
        int u = __shfl_up(v, o, 64);
        if ((t & 63) >= o) v += u;
    }
    __shared__ int wsum[4];
    if ((t & 63) == 63) wsum[t >> 6] = v;
    __syncthreads();
    int wbase = 0;
    for (int w = 0; w < (t >> 6); ++w) wbase += wsum[w];
    int p = bsum[b] + wbase + (v - tot);
    if (base + 3 < n) {
        int4 o4 = make_int4(p, p + d0, p + d0 + d1, p + d0 + d1 + d2);
        *(int4*)&off[base] = o4;
    } else {
        if (base     < n) off[base]     = p;
        if (base + 1 < n) off[base + 1] = p + d0;
        if (base + 2 < n) off[base + 2] = p + d0 + d1;
    }
}

__global__ void fill_kernel(const int* __restrict__ src, const int* __restrict__ dst,
                            const int* __restrict__ off, int* __restrict__ cur,
                            int* __restrict__ csr, int E) {
    int i = blockIdx.x * blockDim.x + threadIdx.x;
    if (i < E) {
        int d = dst[i];
        int p = atomicAdd(&cur[d], 1);
        csr[off[d] + p] = src[i];
    }
}

// Wave-cooperative 128-float row-sum over CSR range [b,e).
// c = (lane&31)*4 float offset, half = lane>>5. Halves take even/odd edges,
// 4-deep ILP each (8 edges / 4KB in flight per wave); cross-half shfl reduce.
template<bool PRESRC>
__device__ __forceinline__ float4 gather_row128(
        const float* __restrict__ hin, const float* __restrict__ nrm,
        const int* __restrict__ csr, int b, int e, int c, int half) {
    float4 a0 = make_float4(0,0,0,0), a1 = a0, a2 = a0, a3 = a0;
    int j = b + half;
    for (; j + 6 < e; j += 8) {
        int s0 = csr[j], s1 = csr[j+2], s2 = csr[j+4], s3 = csr[j+6];
        float4 v0 = *(const float4*)&hin[(size_t)s0 * DIM + c];
        float4 v1 = *(const float4*)&hin[(size_t)s1 * DIM + c];
        float4 v2 = *(const float4*)&hin[(size_t)s2 * DIM + c];
        float4 v3 = *(const float4*)&hin[(size_t)s3 * DIM + c];
        if (PRESRC) {
            float n0 = nrm[s0], n1 = nrm[s1], n2 = nrm[s2], n3 = nrm[s3];
            v0.x*=n0; v0.y*=n0; v0.z*=n0; v0.w*=n0;
            v1.x*=n1; v1.y*=n1; v1.z*=n1; v1.w*=n1;
            v2.x*=n2; v2.y*=n2; v2.z*=n2; v2.w*=n2;
            v3.x*=n3; v3.y*=n3; v3.z*=n3; v3.w*=n3;
        }
        a0.x+=v0.x; a0.y+=v0.y; a0.z+=v0.z; a0.w+=v0.w;
        a1.x+=v1.x; a1.y+=v1.y; a1.z+=v1.z; a1.w+=v1.w;
        a2.x+=v2.x; a2.y+=v2.y; a2.z+=v2.z; a2.w+=v2.w;
        a3.x+=v3.x; a3.y+=v3.y; a3.z+=v3.z; a3.w+=v3.w;
    }
    for (; j < e; j += 2) {
        int s0 = csr[j];
        float4 v = *(const float4*)&hin[(size_t)s0 * DIM + c];
        if (PRESRC) { float n = nrm[s0]; v.x*=n; v.y*=n; v.z*=n; v.w*=n; }
        a0.x+=v.x; a0.y+=v.y; a0.z+=v.z; a0.w+=v.w;
    }
    float4 r;
    r.x = (a0.x+a1.x) + (a2.x+a3.x);
    r.y = (a0.y+a1.y) + (a2.y+a3.y);
    r.z = (a0.z+a1.z) + (a2.z+a3.z);
    r.w = (a0.w+a1.w) + (a2.w+a3.w);
    r.x += __shfl_xor(r.x, 32, 64);
    r.y += __shfl_xor(r.y, 32, 64);
    r.z += __shfl_xor(r.z, 32, 64);
    r.w += __shfl_xor(r.w, 32, 64);
    return r;
}

// Fused layer: aggregate 64 nodes into LDS A-tile, then C = A @ W (128x128),
// relu + norm[row] prescale for the next layer's gather.
template<bool PRESRC>
__global__ __launch_bounds__(256) void fused_kernel(
        const float* __restrict__ hin, const float* __restrict__ W,
        const float* __restrict__ nrm,
        const int* __restrict__ off, const int* __restrict__ csr,
        float* __restrict__ out, int n) {
    __shared__ float As[64 * DIM];
    int t = threadIdx.x;
    int lane = t & 63, wv = t >> 6;
    int half = lane >> 5, c = (lane & 31) * 4;
    int row0 = blockIdx.x * 64;

    // Phase 1: each of 4 waves aggregates 16 contiguous rows.
    for (int r = wv * 16; r < wv * 16 + 16; ++r) {
        int node = row0 + r;
        int b = 0, e = 0; float s = 0.f;
        if (node < n) { b = off[node]; e = off[node + 1]; s = nrm[node]; }
        float4 acc = gather_row128<PRESRC>(hin, nrm, csr, b, e, c, half);
        if (half == 0) {
            acc.x *= s; acc.y *= s; acc.z *= s; acc.w *= s;
            *(float4*)&As[r * DIM + c] = acc;
        }
    }
    __syncthreads();

    // Phase 2: GEMM, 8 rows x 4 cols per thread, W streamed from L2.
    int tc = t & 31, tr = t >> 5;
    float acc[8][4];
#pragma unroll
    for (int i = 0; i < 8; ++i)
#pragma unroll
        for (int j = 0; j < 4; ++j) acc[i][j] = 0.f;

    for (int k4 = 0; k4 < 32; ++k4) {
        float w[4][4];
#pragma unroll
        for (int dk = 0; dk < 4; ++dk) {
            float4 wv4 = *(const float4*)&W[(size_t)(k4 * 4 + dk) * DIM + tc * 4];
            w[dk][0] = wv4.x; w[dk][1] = wv4.y; w[dk][2] = wv4.z; w[dk][3] = wv4.w;
        }
#pragma unroll
        for (int i = 0; i < 8; ++i) {
            float4 a = *(const float4*)&As[(tr * 8 + i) * DIM + k4 * 4];
            float av[4] = {a.x, a.y, a.z, a.w};
#pragma unroll
            for (int dk = 0; dk < 4; ++dk)
#pragma unroll
                for (int j = 0; j < 4; ++j)
                    acc[i][j] += av[dk] * w[dk][j];
        }
    }

#pragma unroll
    for (int i = 0; i < 8; ++i) {
        int row = row0 + tr * 8 + i;
        if (row >= n) continue;
        float s = nrm[row];
        float4 v = make_float4(acc[i][0], acc[i][1], acc[i][2], acc[i][3]);
        v.x = fmaxf(v.x, 0.f) * s; v.y = fmaxf(v.y, 0.f) * s;
        v.z = fmaxf(v.z, 0.f) * s; v.w = fmaxf(v.w, 0.f) * s;
        *(float4*)&out[(size_t)row * DIM + tc * 4] = v;
    }
}

// Standalone GEMM for layer 3 (128 -> outw<=64), no relu/scale.
__global__ __launch_bounds__(256) void gemm3_kernel(
        const float* __restrict__ A, const float* __restrict__ W,
        float* __restrict__ out, int n, int outw) {
    __shared__ float As[64 * DIM];
    int t = threadIdx.x;
    int row0 = blockIdx.x * 64;
    for (int q = t; q < 64 * 32; q += 256) {
        int r = q >> 5, c4 = q & 31;
        int row = row0 + r;
        float4 v = (row < n) ? *(const float4*)&A[(size_t)row * DIM + c4 * 4]
                             : make_float4(0.f, 0.f, 0.f, 0.f);
        *(float4*)&As[r * DIM + c4 * 4] = v;
    }
    __syncthreads();

    int tc = t & 31, tr = t >> 5;
    float acc[8][2];
#pragma unroll
    for (int i = 0; i < 8; ++i) { acc[i][0] = 0.f; acc[i][1] = 0.f; }

    for (int k4 = 0; k4 < 32; ++k4) {
        float w[4][2];
#pragma unroll
        for (int dk = 0; dk < 4; ++dk) {
            int k = k4 * 4 + dk;
            int c0 = tc * 2, c1 = c0 + 1;
            w[dk][0] = (c0 < outw) ? W[(size_t)k * outw + c0] : 0.f;
            w[dk][1] = (c1 < outw) ? W[(size_t)k * outw + c1] : 0.f;
        }
#pragma unroll
        for (int i = 0; i < 8; ++i) {
            float4 a = *(const float4*)&As[(tr * 8 + i) * DIM + k4 * 4];
            float av[4] = {a.x, a.y, a.z, a.w};
#pragma unroll
            for (int dk = 0; dk < 4; ++dk) {
                acc[i][0] += av[dk] * w[dk][0];
                acc[i][1] += av[dk] * w[dk][1];
            }
        }
    }

#pragma unroll
    for (int i = 0; i < 8; ++i) {
        int row = row0 + tr * 8 + i;
        if (row >= n) continue;
#pragma unroll
        for (int j = 0; j < 2; ++j) {
            int cc = tc * 2 + j;
            if (cc < outw) out[(size_t)row * outw + cc] = acc[i][j];
        }
    }
}

// Final aggregation, 40-dim rows. float2 x 20 lanes per half-wave; halves
// take even/odd edges (4-deep ILP each), cross-half shfl reduce.
__global__ __launch_bounds__(256) void agg40_kernel(
        const float* __restrict__ hin, const float* __restrict__ nrm,
        const int* __restrict__ off, const int* __restrict__ csr,
        float* __restrict__ out, int N) {
    int lane = threadIdx.x & 63;
    int node = blockIdx.x * 4 + (threadIdx.x >> 6);
    if (node >= N) return;
    int half = lane >> 5, c2 = lane & 31;
    int b = off[node], e = off[node + 1];
    float x0=0, y0=0, x1=0, y1=0, x2=0, y2=0, x3=0, y3=0;
    if (c2 < 20) {
        int j = b + half;
        for (; j + 6 < e; j += 8) {
            int s0 = csr[j], s1 = csr[j+2], s2 = csr[j+4], s3 = csr[j+6];
            float2 v0 = *(const float2*)&hin[(size_t)s0 * 40 + c2 * 2];
            float2 v1 = *(const float2*)&hin[(size_t)s1 * 40 + c2 * 2];
            float2 v2 = *(const float2*)&hin[(size_t)s2 * 40 + c2 * 2];
            float2 v3 = *(const float2*)&hin[(size_t)s3 * 40 + c2 * 2];
            x0+=v0.x; y0+=v0.y; x1+=v1.x; y1+=v1.y;
            x2+=v2.x; y2+=v2.y; x3+=v3.x; y3+=v3.y;
        }
        for (; j < e; j += 2) {
            float2 v = *(const float2*)&hin[(size_t)csr[j] * 40 + c2 * 2];
            x0+=v.x; y0+=v.y;
        }
    }
    float rx = (x0+x1) + (x2+x3), ry = (y0+y1) + (y2+y3);
    rx += __shfl_xor(rx, 32, 64);
    ry += __shfl_xor(ry, 32, 64);
    if (half == 0 && c2 < 20) {
        float s = nrm[node];
        *(float2*)&out[(size_t)node * 40 + c2 * 2] = make_float2(rx * s, ry * s);
    }
}

extern "C" void kernel_launch(void* const* d_in, const int* in_sizes, int n_in,
                              void* d_out, int out_size, void* d_ws, size_t ws_size,
                              hipStream_t stream) {
    const float* features = (const float*)d_in[0];
    const int*   edges    = (const int*)d_in[1];
    const float* W0       = (const float*)d_in[2];
    const float* W1       = (const float*)d_in[3];
    const float* W2       = (const float*)d_in[4];
    const float* W3       = (const float*)d_in[5];

    const int N = in_sizes[0] / DIM;       // 50000
    const int E = in_sizes[1] / 2;         // 640000
    const int DOUT = out_size / N;         // 40
    const int* src = edges;
    const int* dst = edges + E;

    char* p = (char*)d_ws;
    float* bufA = (float*)p;  p += (size_t)N * DIM * 4;
    float* bufB = (float*)p;  p += (size_t)N * DIM * 4;
    float* nrm  = (float*)p;  p += (size_t)N * 4;
    int*   deg  = (int*)p;    p += (size_t)N * 4;
    int*   cur  = (int*)p;    p += (size_t)N * 4;   // adjacent to deg -> one memset
    int*   off  = (int*)p;    p += (size_t)(N + 1) * 4;
    int*   bsum = (int*)p;    p += 64 * 4;
    int*   csr  = (int*)p;    p += (size_t)E * 4;
    (void)ws_size; (void)n_in;

    hipMemsetAsync(deg, 0, (size_t)N * 2 * sizeof(int), stream);  // deg + cur

    int eb = (E + 255) / 256;
    int G  = (N + CHUNK - 1) / CHUNK;      // 49 chunks
    deg_kernel <<<eb, 256, 0, stream>>>(dst, deg, E);
    scanA_kernel<<<G, 256, 0, stream>>>(deg, nrm, bsum, N);
    scanB_kernel<<<1, 64, 0, stream>>>(bsum, off, G, N);
    scanC_kernel<<<G, 256, 0, stream>>>(deg, bsum, off, N);
    fill_kernel<<<eb, 256, 0, stream>>>(src, dst, off, cur, csr, E);

    int gb = (N + 63) / 64;
    int ab = (N + 3) / 4;
    // layers 0..2 fused: gather(+prescale for layer0) -> LDS -> GEMM+relu+scale
    fused_kernel<true> <<<gb, 256, 0, stream>>>(features, W0, nrm, off, csr, bufA, N);
    fused_kernel<false><<<gb, 256, 0, stream>>>(bufA, W1, nrm, off, csr, bufB, N);
    fused_kernel<false><<<gb, 256, 0, stream>>>(bufB, W2, nrm, off, csr, bufA, N);

    // layer 3: GEMM first (128->40), then aggregate 40-dim into d_out
    gemm3_kernel<<<gb, 256, 0, stream>>>(bufA, W3, bufB, N, DOUT);
    agg40_kernel<<<ab, 256, 0, stream>>>(bufB, nrm, off, csr, (float*)d_out, N);
}